// Round 5
// baseline (373.736 us; speedup 1.0000x reference)
//
#include <hip/hip_runtime.h>
#include <math.h>

namespace {
constexpr int S_ = 4096, D_ = 2048;
constexpr int RS_ = 6, RF_ = 21;
constexpr float EPS_ = 1e-6f;

// ---- DPP 64-lane sum reduction, result broadcast via readlane ----
#define DPP_ADD_(v, ctrl) \
  v += __int_as_float(__builtin_amdgcn_update_dpp(0, __float_as_int(v), ctrl, 0xF, 0xF, true))

__device__ __forceinline__ float wave_sum(float v) {
  DPP_ADD_(v, 0x111);  // row_shr:1
  DPP_ADD_(v, 0x112);  // row_shr:2
  DPP_ADD_(v, 0x114);  // row_shr:4
  DPP_ADD_(v, 0x118);  // row_shr:8
  DPP_ADD_(v, 0x142);  // row_bcast:15
  DPP_ADD_(v, 0x143);  // row_bcast:31
  return __int_as_float(__builtin_amdgcn_readlane(__float_as_int(v), 63));
}

__device__ __forceinline__ float rdlane(float v, int l) {
  return __int_as_float(__builtin_amdgcn_readlane(__float_as_int(v), l));
}

__device__ __forceinline__ float sel_lane(float old, float val, int tgt, int lane) {
  return (lane == tgt) ? val : old;
}

__device__ __forceinline__ float gelu_f(float x) {
  float i2 = 1.5957691216057308f * fmaf(0.044715f * x * x, x, x);
  return x * __builtin_amdgcn_rcpf(1.f + __expf(-i2));
}

__device__ __forceinline__ float dot4(float4 a, float4 b) {
  return fmaf(a.x, b.x, fmaf(a.y, b.y, fmaf(a.z, b.z, a.w * b.w)));
}

__device__ __forceinline__ float4 fma4(float s, float4 a, float4 c) {
  return make_float4(fmaf(s, a.x, c.x), fmaf(s, a.y, c.y), fmaf(s, a.z, c.z),
                     fmaf(s, a.w, c.w));
}
} // namespace

// ---------------- K0: prep — fold norm weights, transpose small mats ----------------
extern "C" __global__ void k_prep(const float* __restrict__ W1, const float* __restrict__ U,
                                  const float* __restrict__ n1w, const float* __restrict__ n2w,
                                  float* __restrict__ w1t, float* __restrict__ ut) {
  int t = blockIdx.x * 256 + threadIdx.x;
  if (t < D_ * RF_) {
    int d = t / RF_, j = t - d * RF_;
    w1t[j * D_ + d] = W1[t] * n2w[d];
  }
  int t2 = t - D_ * RF_;
  if (t2 >= 0 && t2 < D_ * RS_) {
    int d = t2 / RS_, r = t2 - d * RS_;
    ut[r * D_ + d] = U[t2] * n1w[d];
  }
}

// ---------------- K1: RMS1 + U-projection. 2 rows/wave, 2048 blocks ----------------
extern "C" __global__ __launch_bounds__(256, 6) void k_rms1(
    const float* __restrict__ x, const float* __restrict__ ut,
    float* __restrict__ u_t) {
  int tid = threadIdx.x, lane = tid & 63, wid = tid >> 6;
  int row0 = blockIdx.x * 8 + wid * 2;   // 2 consecutive rows per wave
  int b = row0 >> 12;
  int sb = row0 & (S_ - 1);
  int d0 = lane * 4;
  const float* xr = x + (size_t)row0 * D_ + d0;
  const float* up = ut + d0;

  float s2a = 0.f, s2b = 0.f;
  float pa0 = 0.f, pa1 = 0.f, pa2 = 0.f, pa3 = 0.f, pa4 = 0.f, pa5 = 0.f;
  float pb0 = 0.f, pb1 = 0.f, pb2 = 0.f, pb3 = 0.f, pb4 = 0.f, pb5 = 0.f;
#pragma unroll
  for (int k = 0; k < 8; ++k) {
    float4 xa = *(const float4*)(xr + k * 256);
    float4 xb = *(const float4*)(xr + D_ + k * 256);
    s2a += dot4(xa, xa);
    s2b += dot4(xb, xb);
    float4 u0 = *(const float4*)(up + 0 * D_ + k * 256);
    pa0 += dot4(xa, u0); pb0 += dot4(xb, u0);
    float4 u1 = *(const float4*)(up + 1 * D_ + k * 256);
    pa1 += dot4(xa, u1); pb1 += dot4(xb, u1);
    float4 u2 = *(const float4*)(up + 2 * D_ + k * 256);
    pa2 += dot4(xa, u2); pb2 += dot4(xb, u2);
    float4 u3 = *(const float4*)(up + 3 * D_ + k * 256);
    pa3 += dot4(xa, u3); pb3 += dot4(xb, u3);
    float4 u4 = *(const float4*)(up + 4 * D_ + k * 256);
    pa4 += dot4(xa, u4); pb4 += dot4(xb, u4);
    float4 u5 = *(const float4*)(up + 5 * D_ + k * 256);
    pa5 += dot4(xa, u5); pb5 += dot4(xb, u5);
  }
  float ra = rsqrtf(wave_sum(s2a) * (1.0f / D_) + EPS_);
  float rb = rsqrtf(wave_sum(s2b) * (1.0f / D_) + EPS_);
  float va0 = wave_sum(pa0) * ra, vb0 = wave_sum(pb0) * rb;
  float va1 = wave_sum(pa1) * ra, vb1 = wave_sum(pb1) * rb;
  float va2 = wave_sum(pa2) * ra, vb2 = wave_sum(pb2) * rb;
  float va3 = wave_sum(pa3) * ra, vb3 = wave_sum(pb3) * rb;
  float va4 = wave_sum(pa4) * ra, vb4 = wave_sum(pb4) * rb;
  float va5 = wave_sum(pa5) * ra, vb5 = wave_sum(pb5) * rb;

  float uv = 0.f;
  uv = sel_lane(uv, va0, 0, lane);  uv = sel_lane(uv, vb0, 1, lane);
  uv = sel_lane(uv, va1, 2, lane);  uv = sel_lane(uv, vb1, 3, lane);
  uv = sel_lane(uv, va2, 4, lane);  uv = sel_lane(uv, vb2, 5, lane);
  uv = sel_lane(uv, va3, 6, lane);  uv = sel_lane(uv, vb3, 7, lane);
  uv = sel_lane(uv, va4, 8, lane);  uv = sel_lane(uv, vb4, 9, lane);
  uv = sel_lane(uv, va5, 10, lane); uv = sel_lane(uv, vb5, 11, lane);
  if (lane < 2 * RS_) {
    int r = lane >> 1, w = lane & 1;
    u_t[((size_t)b * RS_ + r) * S_ + sb + w] = uv;
  }
}

// ---------------- K2: scan. 1 block of 64 per (b,r); affine prefix over chunks -----
extern "C" __global__ __launch_bounds__(64) void k_scan(
    const float* __restrict__ lam, const float* __restrict__ u_t,
    float* __restrict__ hs_t) {
  int br = blockIdx.x;            // b*6+r
  int r = br % RS_;
  int lane = threadIdx.x;
  float a = 1.f / (1.f + __expf(-lam[r]));
  float a64 = a;
#pragma unroll
  for (int i = 0; i < 6; ++i) a64 *= a64;  // a^64

  const float* ub = u_t + (size_t)br * S_ + lane * 64;
  float vloc = 0.f;
#pragma unroll
  for (int i = 0; i < 16; ++i) {
    float4 uu = *(const float4*)(ub + i * 4);
    vloc = fmaf(a, vloc, uu.x);
    vloc = fmaf(a, vloc, uu.y);
    vloc = fmaf(a, vloc, uu.z);
    vloc = fmaf(a, vloc, uu.w);
  }
  float m = a64, v = vloc;
#pragma unroll
  for (int off = 1; off < 64; off <<= 1) {
    float mu = __shfl_up(m, off);
    float vu = __shfl_up(v, off);
    if (lane >= off) {
      v = fmaf(m, vu, v);
      m *= mu;
    }
  }
  float carry = __shfl_up(v, 1);
  if (lane == 0) carry = 0.f;

  float h = carry;
  float* hb = hs_t + (size_t)br * S_ + lane * 64;
#pragma unroll
  for (int i = 0; i < 16; ++i) {
    float4 uu = *(const float4*)(ub + i * 4);
    float4 o;
    h = fmaf(a, h, uu.x); o.x = h;
    h = fmaf(a, h, uu.y); o.y = h;
    h = fmaf(a, h, uu.z); o.z = h;
    h = fmaf(a, h, uu.w); o.w = h;
    *(float4*)(hb + i * 4) = o;
  }
}

// ---------------- K3: fused V-proj + residual + RMS2 + FFN + residual --------------
// 4 rows/wave, 16 rows/block; weights staged through 32KB LDS, shared by 4 waves.
extern "C" __global__ __launch_bounds__(256, 3) void k_main(
    const float* __restrict__ x, const float* __restrict__ V,
    const float* __restrict__ w1t, const float* __restrict__ W2,
    const float* __restrict__ hs_t, float* __restrict__ out) {
  __shared__ float wbuf[4 * D_];   // 32 KB staging buffer (4 weight rows)

  int tid = threadIdx.x, lane = tid & 63, wid = tid >> 6;
  int row0 = blockIdx.x * 16 + wid * 4;
  int b = row0 >> 12;
  int s0 = row0 & (S_ - 1);
  int d0 = lane * 4;

  // scan values: lane w*6+r holds h[row0+w][r]
  float hv = 0.f;
  if (lane < 4 * RS_) {
    int w = lane / RS_, r = lane - w * RS_;
    hv = hs_t[((size_t)b * RS_ + r) * S_ + s0 + w];
  }

  // issue the HBM x stream early (32 x float4) — overlaps first stage
  float4 xv[4][8];
  const float* xr = x + (size_t)row0 * D_ + d0;
#pragma unroll
  for (int w = 0; w < 4; ++w)
#pragma unroll
    for (int k = 0; k < 8; ++k)
      xv[w][k] = *(const float4*)(xr + w * D_ + k * 256);

  // ---- phase b: x2 = x + hs @ V  (V staged via LDS in 4-row chunks) ----
  for (int r0 = 0; r0 < RS_; r0 += 4) {
    int cnt = (RS_ - r0 < 4) ? (RS_ - r0) : 4;
    __syncthreads();
    {
      const float4* src = (const float4*)(V + r0 * D_);
      float4* dst = (float4*)wbuf;
      for (int i = tid; i < cnt * (D_ / 4); i += 256) dst[i] = src[i];
    }
    __syncthreads();
    for (int rr = 0; rr < cnt; ++rr) {
      int r = r0 + rr;
      const float* wr = wbuf + rr * D_ + d0;
      float h0 = rdlane(hv, 0 * RS_ + r), h1 = rdlane(hv, 1 * RS_ + r);
      float h2 = rdlane(hv, 2 * RS_ + r), h3 = rdlane(hv, 3 * RS_ + r);
#pragma unroll
      for (int k = 0; k < 8; ++k) {
        float4 q = *(const float4*)(wr + k * 256);
        xv[0][k] = fma4(h0, q, xv[0][k]);
        xv[1][k] = fma4(h1, q, xv[1][k]);
        xv[2][k] = fma4(h2, q, xv[2][k]);
        xv[3][k] = fma4(h3, q, xv[3][k]);
      }
    }
  }

  // rms2 per row
  float s20 = 0.f, s21 = 0.f, s22 = 0.f, s23 = 0.f;
#pragma unroll
  for (int k = 0; k < 8; ++k) {
    s20 += dot4(xv[0][k], xv[0][k]);
    s21 += dot4(xv[1][k], xv[1][k]);
    s22 += dot4(xv[2][k], xv[2][k]);
    s23 += dot4(xv[3][k], xv[3][k]);
  }
  float rinv0 = rsqrtf(wave_sum(s20) * (1.0f / D_) + EPS_);
  float rinv1 = rsqrtf(wave_sum(s21) * (1.0f / D_) + EPS_);
  float rinv2 = rsqrtf(wave_sum(s22) * (1.0f / D_) + EPS_);
  float rinv3 = rsqrtf(wave_sum(s23) * (1.0f / D_) + EPS_);

  // ---- phase c: T[w][j] = rinv_w * <x2[w], w1t[j]>  (w1t staged via LDS) ----
  float g0 = 0.f, g1 = 0.f, g2 = 0.f, g3 = 0.f;
  for (int j0 = 0; j0 < RF_; j0 += 4) {
    int cnt = (RF_ - j0 < 4) ? (RF_ - j0) : 4;
    __syncthreads();
    {
      const float4* src = (const float4*)(w1t + j0 * D_);
      float4* dst = (float4*)wbuf;
      for (int i = tid; i < cnt * (D_ / 4); i += 256) dst[i] = src[i];
    }
    __syncthreads();
    for (int jj = 0; jj < cnt; ++jj) {
      const float* wr = wbuf + jj * D_ + d0;
      float p0 = 0.f, p1 = 0.f, p2 = 0.f, p3 = 0.f;
#pragma unroll
      for (int k = 0; k < 8; ++k) {
        float4 q = *(const float4*)(wr + k * 256);
        p0 += dot4(xv[0][k], q);
        p1 += dot4(xv[1][k], q);
        p2 += dot4(xv[2][k], q);
        p3 += dot4(xv[3][k], q);
      }
      int j = j0 + jj;
      float t0 = wave_sum(p0) * rinv0;
      float t1 = wave_sum(p1) * rinv1;
      float t2 = wave_sum(p2) * rinv2;
      float t3 = wave_sum(p3) * rinv3;
      g0 = sel_lane(g0, t0, j, lane);
      g1 = sel_lane(g1, t1, j, lane);
      g2 = sel_lane(g2, t2, j, lane);
      g3 = sel_lane(g3, t3, j, lane);
    }
  }
  g0 = gelu_f(g0); g1 = gelu_f(g1); g2 = gelu_f(g2); g3 = gelu_f(g3);

  // ---- phase d: out = x2 + g @ W2  (W2 staged via LDS) ----
  for (int j0 = 0; j0 < RF_; j0 += 4) {
    int cnt = (RF_ - j0 < 4) ? (RF_ - j0) : 4;
    __syncthreads();
    {
      const float4* src = (const float4*)(W2 + j0 * D_);
      float4* dst = (float4*)wbuf;
      for (int i = tid; i < cnt * (D_ / 4); i += 256) dst[i] = src[i];
    }
    __syncthreads();
    for (int jj = 0; jj < cnt; ++jj) {
      int j = j0 + jj;
      const float* wr = wbuf + jj * D_ + d0;
      float f0 = rdlane(g0, j), f1 = rdlane(g1, j);
      float f2 = rdlane(g2, j), f3 = rdlane(g3, j);
#pragma unroll
      for (int k = 0; k < 8; ++k) {
        float4 q = *(const float4*)(wr + k * 256);
        xv[0][k] = fma4(f0, q, xv[0][k]);
        xv[1][k] = fma4(f1, q, xv[1][k]);
        xv[2][k] = fma4(f2, q, xv[2][k]);
        xv[3][k] = fma4(f3, q, xv[3][k]);
      }
    }
  }

  float* orow = out + (size_t)row0 * D_ + d0;
#pragma unroll
  for (int w = 0; w < 4; ++w)
#pragma unroll
    for (int k = 0; k < 8; ++k)
      *(float4*)(orow + w * D_ + k * 256) = xv[w][k];
}

extern "C" void kernel_launch(void* const* d_in, const int* in_sizes, int n_in,
                              void* d_out, int out_size, void* d_ws, size_t ws_size,
                              hipStream_t stream) {
  const float* x   = (const float*)d_in[0];
  const float* n1w = (const float*)d_in[1];
  const float* U   = (const float*)d_in[2];
  const float* lam = (const float*)d_in[3];
  const float* V   = (const float*)d_in[4];
  const float* n2w = (const float*)d_in[5];
  const float* W1  = (const float*)d_in[6];
  const float* W2  = (const float*)d_in[7];
  float* out = (float*)d_out;
  float* ws  = (float*)d_ws;

  // ws layout (floats): u_t[98304] | hs_t[98304] | w1t[43008] | ut[12288]
  float* u_t  = ws;
  float* hs_t = ws + 98304;
  float* w1t  = ws + 196608;
  float* ut   = ws + 239616;

  k_prep<<<216, 256, 0, stream>>>(W1, U, n1w, n2w, w1t, ut);
  k_rms1<<<2048, 256, 0, stream>>>(x, ut, u_t);
  k_scan<<<24, 64, 0, stream>>>(lam, u_t, hs_t);
  k_main<<<1024, 256, 0, stream>>>(x, V, w1t, W2, hs_t, out);
}

// Round 7
// 332.804 us; speedup vs baseline: 1.1230x; 1.1230x over previous
//
#include <hip/hip_runtime.h>
#include <math.h>

namespace {
constexpr int S_ = 4096, D_ = 2048;
constexpr int RS_ = 6, RF_ = 21;
constexpr float EPS_ = 1e-6f;

typedef float floatx4 __attribute__((ext_vector_type(4)));

// ---- DPP 64-lane sum reduction, result broadcast via readlane ----
#define DPP_ADD_(v, ctrl) \
  v += __int_as_float(__builtin_amdgcn_update_dpp(0, __float_as_int(v), ctrl, 0xF, 0xF, true))

__device__ __forceinline__ float wave_sum(float v) {
  DPP_ADD_(v, 0x111);  // row_shr:1
  DPP_ADD_(v, 0x112);  // row_shr:2
  DPP_ADD_(v, 0x114);  // row_shr:4
  DPP_ADD_(v, 0x118);  // row_shr:8
  DPP_ADD_(v, 0x142);  // row_bcast:15
  DPP_ADD_(v, 0x143);  // row_bcast:31
  return __int_as_float(__builtin_amdgcn_readlane(__float_as_int(v), 63));
}

__device__ __forceinline__ float rdlane(float v, int l) {
  return __int_as_float(__builtin_amdgcn_readlane(__float_as_int(v), l));
}

__device__ __forceinline__ float sel_lane(float old, float val, int tgt, int lane) {
  return (lane == tgt) ? val : old;
}

__device__ __forceinline__ float gelu_f(float x) {
  float i2 = 1.5957691216057308f * fmaf(0.044715f * x * x, x, x);
  return x * __builtin_amdgcn_rcpf(1.f + __expf(-i2));
}

__device__ __forceinline__ float dot4(float4 a, float4 b) {
  return fmaf(a.x, b.x, fmaf(a.y, b.y, fmaf(a.z, b.z, a.w * b.w)));
}

__device__ __forceinline__ float4 fma4(float s, float4 a, float4 c) {
  return make_float4(fmaf(s, a.x, c.x), fmaf(s, a.y, c.y), fmaf(s, a.z, c.z),
                     fmaf(s, a.w, c.w));
}

// load a half weight-row slice: 4 x float4 at p, p+256, p+512, p+768
__device__ __forceinline__ void ld4(float4 (&q)[4], const float* p) {
  q[0] = *(const float4*)(p);
  q[1] = *(const float4*)(p + 256);
  q[2] = *(const float4*)(p + 512);
  q[3] = *(const float4*)(p + 768);
}

__device__ __forceinline__ void nt_store4(float4 v, float* p) {
  floatx4 t = {v.x, v.y, v.z, v.w};
  __builtin_nontemporal_store(t, (floatx4*)p);
}
} // namespace

// ---------------- K0: prep — fold norm weights, transpose small mats ----------------
extern "C" __global__ void k_prep(const float* __restrict__ W1, const float* __restrict__ U,
                                  const float* __restrict__ n1w, const float* __restrict__ n2w,
                                  float* __restrict__ w1t, float* __restrict__ ut) {
  int t = blockIdx.x * 256 + threadIdx.x;
  if (t < D_ * RF_) {
    int d = t / RF_, j = t - d * RF_;
    w1t[j * D_ + d] = W1[t] * n2w[d];
  }
  int t2 = t - D_ * RF_;
  if (t2 >= 0 && t2 < D_ * RS_) {
    int d = t2 / RS_, r = t2 - d * RS_;
    ut[r * D_ + d] = U[t2] * n1w[d];
  }
}

// ---------------- K1: RMS1 + U-projection. 2 rows/wave, 2048 blocks ----------------
extern "C" __global__ __launch_bounds__(256, 6) void k_rms1(
    const float* __restrict__ x, const float* __restrict__ ut,
    float* __restrict__ u_t) {
  int tid = threadIdx.x, lane = tid & 63, wid = tid >> 6;
  int row0 = blockIdx.x * 8 + wid * 2;   // 2 consecutive rows per wave
  int b = row0 >> 12;
  int sb = row0 & (S_ - 1);
  int d0 = lane * 4;
  const float* xr = x + (size_t)row0 * D_ + d0;
  const float* up = ut + d0;

  float s2a = 0.f, s2b = 0.f;
  float pa0 = 0.f, pa1 = 0.f, pa2 = 0.f, pa3 = 0.f, pa4 = 0.f, pa5 = 0.f;
  float pb0 = 0.f, pb1 = 0.f, pb2 = 0.f, pb3 = 0.f, pb4 = 0.f, pb5 = 0.f;
#pragma unroll
  for (int k = 0; k < 8; ++k) {
    float4 xa = *(const float4*)(xr + k * 256);
    float4 xb = *(const float4*)(xr + D_ + k * 256);
    s2a += dot4(xa, xa);
    s2b += dot4(xb, xb);
    float4 u0 = *(const float4*)(up + 0 * D_ + k * 256);
    pa0 += dot4(xa, u0); pb0 += dot4(xb, u0);
    float4 u1 = *(const float4*)(up + 1 * D_ + k * 256);
    pa1 += dot4(xa, u1); pb1 += dot4(xb, u1);
    float4 u2 = *(const float4*)(up + 2 * D_ + k * 256);
    pa2 += dot4(xa, u2); pb2 += dot4(xb, u2);
    float4 u3 = *(const float4*)(up + 3 * D_ + k * 256);
    pa3 += dot4(xa, u3); pb3 += dot4(xb, u3);
    float4 u4 = *(const float4*)(up + 4 * D_ + k * 256);
    pa4 += dot4(xa, u4); pb4 += dot4(xb, u4);
    float4 u5 = *(const float4*)(up + 5 * D_ + k * 256);
    pa5 += dot4(xa, u5); pb5 += dot4(xb, u5);
  }
  float ra = rsqrtf(wave_sum(s2a) * (1.0f / D_) + EPS_);
  float rb = rsqrtf(wave_sum(s2b) * (1.0f / D_) + EPS_);
  float va0 = wave_sum(pa0) * ra, vb0 = wave_sum(pb0) * rb;
  float va1 = wave_sum(pa1) * ra, vb1 = wave_sum(pb1) * rb;
  float va2 = wave_sum(pa2) * ra, vb2 = wave_sum(pb2) * rb;
  float va3 = wave_sum(pa3) * ra, vb3 = wave_sum(pb3) * rb;
  float va4 = wave_sum(pa4) * ra, vb4 = wave_sum(pb4) * rb;
  float va5 = wave_sum(pa5) * ra, vb5 = wave_sum(pb5) * rb;

  float uv = 0.f;
  uv = sel_lane(uv, va0, 0, lane);  uv = sel_lane(uv, vb0, 1, lane);
  uv = sel_lane(uv, va1, 2, lane);  uv = sel_lane(uv, vb1, 3, lane);
  uv = sel_lane(uv, va2, 4, lane);  uv = sel_lane(uv, vb2, 5, lane);
  uv = sel_lane(uv, va3, 6, lane);  uv = sel_lane(uv, vb3, 7, lane);
  uv = sel_lane(uv, va4, 8, lane);  uv = sel_lane(uv, vb4, 9, lane);
  uv = sel_lane(uv, va5, 10, lane); uv = sel_lane(uv, vb5, 11, lane);
  if (lane < 2 * RS_) {
    int r = lane >> 1, w = lane & 1;
    u_t[((size_t)b * RS_ + r) * S_ + sb + w] = uv;
  }
}

// ---------------- K2: scan. 1 block of 64 per (b,r); affine prefix over chunks -----
extern "C" __global__ __launch_bounds__(64) void k_scan(
    const float* __restrict__ lam, const float* __restrict__ u_t,
    float* __restrict__ hs_t) {
  int br = blockIdx.x;            // b*6+r
  int r = br % RS_;
  int lane = threadIdx.x;
  float a = 1.f / (1.f + __expf(-lam[r]));
  float a64 = a;
#pragma unroll
  for (int i = 0; i < 6; ++i) a64 *= a64;  // a^64

  const float* ub = u_t + (size_t)br * S_ + lane * 64;
  float vloc = 0.f;
#pragma unroll
  for (int i = 0; i < 16; ++i) {
    float4 uu = *(const float4*)(ub + i * 4);
    vloc = fmaf(a, vloc, uu.x);
    vloc = fmaf(a, vloc, uu.y);
    vloc = fmaf(a, vloc, uu.z);
    vloc = fmaf(a, vloc, uu.w);
  }
  float m = a64, v = vloc;
#pragma unroll
  for (int off = 1; off < 64; off <<= 1) {
    float mu = __shfl_up(m, off);
    float vu = __shfl_up(v, off);
    if (lane >= off) {
      v = fmaf(m, vu, v);
      m *= mu;
    }
  }
  float carry = __shfl_up(v, 1);
  if (lane == 0) carry = 0.f;

  float h = carry;
  float* hb = hs_t + (size_t)br * S_ + lane * 64;
#pragma unroll
  for (int i = 0; i < 16; ++i) {
    float4 uu = *(const float4*)(ub + i * 4);
    float4 o;
    h = fmaf(a, h, uu.x); o.x = h;
    h = fmaf(a, h, uu.y); o.y = h;
    h = fmaf(a, h, uu.z); o.z = h;
    h = fmaf(a, h, uu.w); o.w = h;
    *(float4*)(hb + i * 4) = o;
  }
}

// ---------------- K3: fused V-proj + residual + RMS2 + FFN + residual --------------
// 4 rows/wave, no LDS/barriers; depth-3 half-row pipelined weight stream (q0..q3).
#define DOT_HALF(Q, KB)                                           \
  {                                                               \
    p0 += dot4(xv[0][KB], Q[0]);   p0 += dot4(xv[0][KB+1], Q[1]); \
    p0 += dot4(xv[0][KB+2], Q[2]); p0 += dot4(xv[0][KB+3], Q[3]); \
    p1 += dot4(xv[1][KB], Q[0]);   p1 += dot4(xv[1][KB+1], Q[1]); \
    p1 += dot4(xv[1][KB+2], Q[2]); p1 += dot4(xv[1][KB+3], Q[3]); \
    p2 += dot4(xv[2][KB], Q[0]);   p2 += dot4(xv[2][KB+1], Q[1]); \
    p2 += dot4(xv[2][KB+2], Q[2]); p2 += dot4(xv[2][KB+3], Q[3]); \
    p3 += dot4(xv[3][KB], Q[0]);   p3 += dot4(xv[3][KB+1], Q[1]); \
    p3 += dot4(xv[3][KB+2], Q[2]); p3 += dot4(xv[3][KB+3], Q[3]); \
  }

#define FMA_HALF(Q, KB, F0, F1, F2, F3)                           \
  {                                                               \
    xv[0][KB]   = fma4(F0, Q[0], xv[0][KB]);                      \
    xv[0][KB+1] = fma4(F0, Q[1], xv[0][KB+1]);                    \
    xv[0][KB+2] = fma4(F0, Q[2], xv[0][KB+2]);                    \
    xv[0][KB+3] = fma4(F0, Q[3], xv[0][KB+3]);                    \
    xv[1][KB]   = fma4(F1, Q[0], xv[1][KB]);                      \
    xv[1][KB+1] = fma4(F1, Q[1], xv[1][KB+1]);                    \
    xv[1][KB+2] = fma4(F1, Q[2], xv[1][KB+2]);                    \
    xv[1][KB+3] = fma4(F1, Q[3], xv[1][KB+3]);                    \
    xv[2][KB]   = fma4(F2, Q[0], xv[2][KB]);                      \
    xv[2][KB+1] = fma4(F2, Q[1], xv[2][KB+1]);                    \
    xv[2][KB+2] = fma4(F2, Q[2], xv[2][KB+2]);                    \
    xv[2][KB+3] = fma4(F2, Q[3], xv[2][KB+3]);                    \
    xv[3][KB]   = fma4(F3, Q[0], xv[3][KB]);                      \
    xv[3][KB+1] = fma4(F3, Q[1], xv[3][KB+1]);                    \
    xv[3][KB+2] = fma4(F3, Q[2], xv[3][KB+2]);                    \
    xv[3][KB+3] = fma4(F3, Q[3], xv[3][KB+3]);                    \
  }

#define REDUCE_PACK(J)                                            \
  {                                                               \
    float t0 = wave_sum(p0) * rinv0;                              \
    float t1 = wave_sum(p1) * rinv1;                              \
    float t2 = wave_sum(p2) * rinv2;                              \
    float t3 = wave_sum(p3) * rinv3;                              \
    g0 = sel_lane(g0, t0, (J), lane);                             \
    g1 = sel_lane(g1, t1, (J), lane);                             \
    g2 = sel_lane(g2, t2, (J), lane);                             \
    g3 = sel_lane(g3, t3, (J), lane);                             \
  }

extern "C" __global__ __launch_bounds__(256, 2) void k_main(
    const float* __restrict__ x, const float* __restrict__ V,
    const float* __restrict__ w1t, const float* __restrict__ W2,
    const float* __restrict__ hs_t, float* __restrict__ out) {
  int tid = threadIdx.x, lane = tid & 63, wid = tid >> 6;
  int row0 = blockIdx.x * 16 + wid * 4;
  int b = row0 >> 12;
  int s0 = row0 & (S_ - 1);
  int d0 = lane * 4;

  // x stream first (longest latency), then scan values, then V prologue
  float4 xv[4][8];
  const float* xr = x + (size_t)row0 * D_ + d0;
#pragma unroll
  for (int w = 0; w < 4; ++w)
#pragma unroll
    for (int k = 0; k < 8; ++k)
      xv[w][k] = *(const float4*)(xr + w * D_ + k * 256);

  float hv = 0.f;
  if (lane < 4 * RS_) {
    int w = lane / RS_, r = lane - w * RS_;
    hv = hs_t[((size_t)b * RS_ + r) * S_ + s0 + w];
  }

  float4 q0[4], q1[4], q2[4], q3[4];

  // ---- phase b: x2 = x + hs @ V  (3 pairs, depth-3 half-row pipeline) ----
  const float* Vp = V + d0;
  ld4(q0, Vp);              // lo0
  ld4(q1, Vp + 1024);       // hi0
  ld4(q2, Vp + D_);         // lo1
#pragma unroll
  for (int rp = 0; rp < 3; ++rp) {
    int r0 = 2 * rp, r1 = 2 * rp + 1;
    ld4(q3, Vp + r1 * D_ + 1024);                    // hi_{r1}
    float h0 = rdlane(hv, 0 * RS_ + r0), h1 = rdlane(hv, 1 * RS_ + r0);
    float h2 = rdlane(hv, 2 * RS_ + r0), h3 = rdlane(hv, 3 * RS_ + r0);
    FMA_HALF(q0, 0, h0, h1, h2, h3);
    if (rp < 2) ld4(q0, Vp + (r0 + 2) * D_);         // lo_{r0+2}
    FMA_HALF(q1, 4, h0, h1, h2, h3);
    if (rp < 2) ld4(q1, Vp + (r1 + 1) * D_ + 1024);  // hi_{r1+1}
    float e0 = rdlane(hv, 0 * RS_ + r1), e1 = rdlane(hv, 1 * RS_ + r1);
    float e2 = rdlane(hv, 2 * RS_ + r1), e3 = rdlane(hv, 3 * RS_ + r1);
    FMA_HALF(q2, 0, e0, e1, e2, e3);
    if (rp < 2) ld4(q2, Vp + (r1 + 2) * D_);         // lo_{r1+2}
    FMA_HALF(q3, 4, e0, e1, e2, e3);
  }

  // W1 prologue issues before the rms2 DPP chains (covers L2 latency)
  const float* Wp = w1t + d0;
  ld4(q0, Wp);              // lo0
  ld4(q1, Wp + 1024);       // hi0
  ld4(q2, Wp + D_);         // lo1

  // rms2 per row
  float s20 = 0.f, s21 = 0.f, s22 = 0.f, s23 = 0.f;
#pragma unroll
  for (int k = 0; k < 8; ++k) {
    s20 += dot4(xv[0][k], xv[0][k]);
    s21 += dot4(xv[1][k], xv[1][k]);
    s22 += dot4(xv[2][k], xv[2][k]);
    s23 += dot4(xv[3][k], xv[3][k]);
  }
  float rinv0 = rsqrtf(wave_sum(s20) * (1.0f / D_) + EPS_);
  float rinv1 = rsqrtf(wave_sum(s21) * (1.0f / D_) + EPS_);
  float rinv2 = rsqrtf(wave_sum(s22) * (1.0f / D_) + EPS_);
  float rinv3 = rsqrtf(wave_sum(s23) * (1.0f / D_) + EPS_);

  // ---- phase c: T[w][j] = rinv_w * <x2[w], w1t[j]>  (10 pairs + remainder j=20) ----
  float g0 = 0.f, g1 = 0.f, g2 = 0.f, g3 = 0.f;
  float p0, p1, p2, p3;
  for (int jp = 0; jp < 10; ++jp) {
    int j0 = 2 * jp, j1 = 2 * jp + 1;
    ld4(q3, Wp + j1 * D_ + 1024);                    // hi_{j1}
    p0 = p1 = p2 = p3 = 0.f;
    DOT_HALF(q0, 0);
    ld4(q0, Wp + (j0 + 2) * D_);                     // lo_{j0+2} (<=20, in bounds)
    DOT_HALF(q1, 4);
    REDUCE_PACK(j0);
    ld4(q1, Wp + (j1 + 1) * D_ + 1024);              // hi_{j1+1} (<=20)
    p0 = p1 = p2 = p3 = 0.f;
    DOT_HALF(q2, 0);
    if (jp < 9) ld4(q2, Wp + (j1 + 2) * D_);         // lo_{j1+2}
    DOT_HALF(q3, 4);
    REDUCE_PACK(j1);
  }
  // remainder j=20: q0=lo20, q1=hi20
  p0 = p1 = p2 = p3 = 0.f;
  DOT_HALF(q0, 0);
  DOT_HALF(q1, 4);
  // W2 prologue before the final reduce+gelu (covers L2 latency)
  const float* W2p = W2 + d0;
  REDUCE_PACK(20);
  ld4(q0, W2p);             // lo0
  ld4(q1, W2p + 1024);      // hi0
  ld4(q2, W2p + D_);        // lo1
  g0 = gelu_f(g0); g1 = gelu_f(g1); g2 = gelu_f(g2); g3 = gelu_f(g3);

  // ---- phase d: out = x2 + g @ W2  (same pipeline, FMA accumulate) ----
  for (int jp = 0; jp < 10; ++jp) {
    int j0 = 2 * jp, j1 = 2 * jp + 1;
    ld4(q3, W2p + j1 * D_ + 1024);                   // hi_{j1}
    float f0 = rdlane(g0, j0), f1 = rdlane(g1, j0);
    float f2 = rdlane(g2, j0), f3 = rdlane(g3, j0);
    FMA_HALF(q0, 0, f0, f1, f2, f3);
    ld4(q0, W2p + (j0 + 2) * D_);                    // lo_{j0+2}
    FMA_HALF(q1, 4, f0, f1, f2, f3);
    ld4(q1, W2p + (j1 + 1) * D_ + 1024);             // hi_{j1+1}
    float e0 = rdlane(g0, j1), e1 = rdlane(g1, j1);
    float e2 = rdlane(g2, j1), e3 = rdlane(g3, j1);
    FMA_HALF(q2, 0, e0, e1, e2, e3);
    if (jp < 9) ld4(q2, W2p + (j1 + 2) * D_);        // lo_{j1+2}
    FMA_HALF(q3, 4, e0, e1, e2, e3);
  }
  {
    float f0 = rdlane(g0, 20), f1 = rdlane(g1, 20);
    float f2 = rdlane(g2, 20), f3 = rdlane(g3, 20);
    FMA_HALF(q0, 0, f0, f1, f2, f3);
    FMA_HALF(q1, 4, f0, f1, f2, f3);
  }

  float* orow = out + (size_t)row0 * D_ + d0;
#pragma unroll
  for (int w = 0; w < 4; ++w)
#pragma unroll
    for (int k = 0; k < 8; ++k)
      nt_store4(xv[w][k], orow + w * D_ + k * 256);
}

extern "C" void kernel_launch(void* const* d_in, const int* in_sizes, int n_in,
                              void* d_out, int out_size, void* d_ws, size_t ws_size,
                              hipStream_t stream) {
  const float* x   = (const float*)d_in[0];
  const float* n1w = (const float*)d_in[1];
  const float* U   = (const float*)d_in[2];
  const float* lam = (const float*)d_in[3];
  const float* V   = (const float*)d_in[4];
  const float* n2w = (const float*)d_in[5];
  const float* W1  = (const float*)d_in[6];
  const float* W2  = (const float*)d_in[7];
  float* out = (float*)d_out;
  float* ws  = (float*)d_ws;

  // ws layout (floats): u_t[98304] | hs_t[98304] | w1t[43008] | ut[12288]
  float* u_t  = ws;
  float* hs_t = ws + 98304;
  float* w1t  = ws + 196608;
  float* ut   = ws + 239616;

  k_prep<<<216, 256, 0, stream>>>(W1, U, n1w, n2w, w1t, ut);
  k_rms1<<<2048, 256, 0, stream>>>(x, ut, u_t);
  k_scan<<<24, 64, 0, stream>>>(lam, u_t, hs_t);
  k_main<<<1024, 256, 0, stream>>>(x, V, w1t, W2, hs_t, out);
}

// Round 8
// 327.333 us; speedup vs baseline: 1.1418x; 1.0167x over previous
//
#include <hip/hip_runtime.h>
#include <math.h>

namespace {
constexpr int S_ = 4096, D_ = 2048;
constexpr int RS_ = 6, RF_ = 21;
constexpr float EPS_ = 1e-6f;

typedef float floatx4 __attribute__((ext_vector_type(4)));
typedef short bf16x8 __attribute__((ext_vector_type(8)));

// ---- DPP 64-lane sum reduction, result broadcast via readlane ----
#define DPP_ADD_(v, ctrl) \
  v += __int_as_float(__builtin_amdgcn_update_dpp(0, __float_as_int(v), ctrl, 0xF, 0xF, true))

__device__ __forceinline__ float wave_sum(float v) {
  DPP_ADD_(v, 0x111);  // row_shr:1
  DPP_ADD_(v, 0x112);  // row_shr:2
  DPP_ADD_(v, 0x114);  // row_shr:4
  DPP_ADD_(v, 0x118);  // row_shr:8
  DPP_ADD_(v, 0x142);  // row_bcast:15
  DPP_ADD_(v, 0x143);  // row_bcast:31
  return __int_as_float(__builtin_amdgcn_readlane(__float_as_int(v), 63));
}

__device__ __forceinline__ float rdlane(float v, int l) {
  return __int_as_float(__builtin_amdgcn_readlane(__float_as_int(v), l));
}

__device__ __forceinline__ float gelu_f(float x) {
  float i2 = 1.5957691216057308f * fmaf(0.044715f * x * x, x, x);
  return x * __builtin_amdgcn_rcpf(1.f + __expf(-i2));
}

__device__ __forceinline__ float dot4(float4 a, float4 b) {
  return fmaf(a.x, b.x, fmaf(a.y, b.y, fmaf(a.z, b.z, a.w * b.w)));
}

__device__ __forceinline__ float4 fma4(float s, float4 a, float4 c) {
  return make_float4(fmaf(s, a.x, c.x), fmaf(s, a.y, c.y), fmaf(s, a.z, c.z),
                     fmaf(s, a.w, c.w));
}

__device__ __forceinline__ void ld4(float4 (&q)[4], const float* p) {
  q[0] = *(const float4*)(p);
  q[1] = *(const float4*)(p + 256);
  q[2] = *(const float4*)(p + 512);
  q[3] = *(const float4*)(p + 768);
}

__device__ __forceinline__ void nt_store4(float4 v, float* p) {
  floatx4 t = {v.x, v.y, v.z, v.w};
  __builtin_nontemporal_store(t, (floatx4*)p);
}

// RTN float->bf16 (matches HW rounding closely enough for our tolerance)
__device__ __forceinline__ unsigned int bf16_bits(float f) {
  unsigned int u = __float_as_uint(f);
  return (u + 0x7fffu + ((u >> 16) & 1u)) >> 16;
}
__device__ __forceinline__ unsigned int pack_bf16(float a, float b) {
  return bf16_bits(a) | (bf16_bits(b) << 16);
}
} // namespace

// ---------------- K0: prep — W1 bf16 B-fragments (n2w folded), ut for rms1 ---------
// w1f element t = ((kt*2+nt)*64 + lane)*8 + i  holds  W1[k][j]*n2w[k] as bf16,
// with k = kt*32 + (lane>>4)*8 + i,  j = nt*16 + (lane&15)  (0 if j >= 21).
extern "C" __global__ void k_prep(const float* __restrict__ W1, const float* __restrict__ U,
                                  const float* __restrict__ n1w, const float* __restrict__ n2w,
                                  unsigned short* __restrict__ w1f, float* __restrict__ ut) {
  int t = blockIdx.x * 256 + threadIdx.x;
  if (t < 65536) {
    int i = t & 7, lane = (t >> 3) & 63, ntk = t >> 9;
    int nt = ntk & 1, kt = ntk >> 1;
    int k = kt * 32 + ((lane >> 4) << 3) + i;
    int j = nt * 16 + (lane & 15);
    float v = (j < RF_) ? W1[k * RF_ + j] * n2w[k] : 0.f;
    w1f[t] = (unsigned short)bf16_bits(v);
  } else {
    int t2 = t - 65536;
    if (t2 < D_ * RS_) {
      int d = t2 / RS_, r = t2 - d * RS_;
      ut[r * D_ + d] = U[t2] * n1w[d];
    }
  }
}

// ---------------- K1: RMS1 + U-projection. 2 rows/wave, 2048 blocks ----------------
extern "C" __global__ __launch_bounds__(256, 6) void k_rms1(
    const float* __restrict__ x, const float* __restrict__ ut,
    float* __restrict__ u_t) {
  int tid = threadIdx.x, lane = tid & 63, wid = tid >> 6;
  int row0 = blockIdx.x * 8 + wid * 2;
  int b = row0 >> 12;
  int sb = row0 & (S_ - 1);
  int d0 = lane * 4;
  const float* xr = x + (size_t)row0 * D_ + d0;
  const float* up = ut + d0;

  float s2a = 0.f, s2b = 0.f;
  float pa0 = 0.f, pa1 = 0.f, pa2 = 0.f, pa3 = 0.f, pa4 = 0.f, pa5 = 0.f;
  float pb0 = 0.f, pb1 = 0.f, pb2 = 0.f, pb3 = 0.f, pb4 = 0.f, pb5 = 0.f;
#pragma unroll
  for (int k = 0; k < 8; ++k) {
    float4 xa = *(const float4*)(xr + k * 256);
    float4 xb = *(const float4*)(xr + D_ + k * 256);
    s2a += dot4(xa, xa);
    s2b += dot4(xb, xb);
    float4 u0 = *(const float4*)(up + 0 * D_ + k * 256);
    pa0 += dot4(xa, u0); pb0 += dot4(xb, u0);
    float4 u1 = *(const float4*)(up + 1 * D_ + k * 256);
    pa1 += dot4(xa, u1); pb1 += dot4(xb, u1);
    float4 u2 = *(const float4*)(up + 2 * D_ + k * 256);
    pa2 += dot4(xa, u2); pb2 += dot4(xb, u2);
    float4 u3 = *(const float4*)(up + 3 * D_ + k * 256);
    pa3 += dot4(xa, u3); pb3 += dot4(xb, u3);
    float4 u4 = *(const float4*)(up + 4 * D_ + k * 256);
    pa4 += dot4(xa, u4); pb4 += dot4(xb, u4);
    float4 u5 = *(const float4*)(up + 5 * D_ + k * 256);
    pa5 += dot4(xa, u5); pb5 += dot4(xb, u5);
  }
  float ra = rsqrtf(wave_sum(s2a) * (1.0f / D_) + EPS_);
  float rb = rsqrtf(wave_sum(s2b) * (1.0f / D_) + EPS_);
  float va0 = wave_sum(pa0) * ra, vb0 = wave_sum(pb0) * rb;
  float va1 = wave_sum(pa1) * ra, vb1 = wave_sum(pb1) * rb;
  float va2 = wave_sum(pa2) * ra, vb2 = wave_sum(pb2) * rb;
  float va3 = wave_sum(pa3) * ra, vb3 = wave_sum(pb3) * rb;
  float va4 = wave_sum(pa4) * ra, vb4 = wave_sum(pb4) * rb;
  float va5 = wave_sum(pa5) * ra, vb5 = wave_sum(pb5) * rb;

  float uv = 0.f;
  uv = (lane == 0) ? va0 : uv;  uv = (lane == 1) ? vb0 : uv;
  uv = (lane == 2) ? va1 : uv;  uv = (lane == 3) ? vb1 : uv;
  uv = (lane == 4) ? va2 : uv;  uv = (lane == 5) ? vb2 : uv;
  uv = (lane == 6) ? va3 : uv;  uv = (lane == 7) ? vb3 : uv;
  uv = (lane == 8) ? va4 : uv;  uv = (lane == 9) ? vb4 : uv;
  uv = (lane == 10) ? va5 : uv; uv = (lane == 11) ? vb5 : uv;
  if (lane < 2 * RS_) {
    int r = lane >> 1, w = lane & 1;
    u_t[((size_t)b * RS_ + r) * S_ + sb + w] = uv;
  }
}

// ---------------- K2: scan. 1 block of 64 per (b,r); affine prefix over chunks -----
extern "C" __global__ __launch_bounds__(64) void k_scan(
    const float* __restrict__ lam, const float* __restrict__ u_t,
    float* __restrict__ hs_t) {
  int br = blockIdx.x;
  int r = br % RS_;
  int lane = threadIdx.x;
  float a = 1.f / (1.f + __expf(-lam[r]));
  float a64 = a;
#pragma unroll
  for (int i = 0; i < 6; ++i) a64 *= a64;

  const float* ub = u_t + (size_t)br * S_ + lane * 64;
  float vloc = 0.f;
#pragma unroll
  for (int i = 0; i < 16; ++i) {
    float4 uu = *(const float4*)(ub + i * 4);
    vloc = fmaf(a, vloc, uu.x);
    vloc = fmaf(a, vloc, uu.y);
    vloc = fmaf(a, vloc, uu.z);
    vloc = fmaf(a, vloc, uu.w);
  }
  float m = a64, v = vloc;
#pragma unroll
  for (int off = 1; off < 64; off <<= 1) {
    float mu = __shfl_up(m, off);
    float vu = __shfl_up(v, off);
    if (lane >= off) {
      v = fmaf(m, vu, v);
      m *= mu;
    }
  }
  float carry = __shfl_up(v, 1);
  if (lane == 0) carry = 0.f;

  float h = carry;
  float* hb = hs_t + (size_t)br * S_ + lane * 64;
#pragma unroll
  for (int i = 0; i < 16; ++i) {
    float4 uu = *(const float4*)(ub + i * 4);
    float4 o;
    h = fmaf(a, h, uu.x); o.x = h;
    h = fmaf(a, h, uu.y); o.y = h;
    h = fmaf(a, h, uu.z); o.z = h;
    h = fmaf(a, h, uu.w); o.w = h;
    *(float4*)(hb + i * 4) = o;
  }
}

// ---------------- K3: V-proj + residual + RMS2 + [MFMA GEMM1] + gelu + FFN2 --------
#define FMA_HALF(Q, KB, F0, F1, F2, F3)                           \
  {                                                               \
    xv[0][KB]   = fma4(F0, Q[0], xv[0][KB]);                      \
    xv[0][KB+1] = fma4(F0, Q[1], xv[0][KB+1]);                    \
    xv[0][KB+2] = fma4(F0, Q[2], xv[0][KB+2]);                    \
    xv[0][KB+3] = fma4(F0, Q[3], xv[0][KB+3]);                    \
    xv[1][KB]   = fma4(F1, Q[0], xv[1][KB]);                      \
    xv[1][KB+1] = fma4(F1, Q[1], xv[1][KB+1]);                    \
    xv[1][KB+2] = fma4(F1, Q[2], xv[1][KB+2]);                    \
    xv[1][KB+3] = fma4(F1, Q[3], xv[1][KB+3]);                    \
    xv[2][KB]   = fma4(F2, Q[0], xv[2][KB]);                      \
    xv[2][KB+1] = fma4(F2, Q[1], xv[2][KB+1]);                    \
    xv[2][KB+2] = fma4(F2, Q[2], xv[2][KB+2]);                    \
    xv[2][KB+3] = fma4(F2, Q[3], xv[2][KB+3]);                    \
    xv[3][KB]   = fma4(F3, Q[0], xv[3][KB]);                      \
    xv[3][KB+1] = fma4(F3, Q[1], xv[3][KB+1]);                    \
    xv[3][KB+2] = fma4(F3, Q[2], xv[3][KB+2]);                    \
    xv[3][KB+3] = fma4(F3, Q[3], xv[3][KB+3]);                    \
  }

// stage one owner row W (block row wid*4+W) into A-fragment LDS, rinv folded
#define STAGE(W, RW)                                                        \
  {                                                                         \
    int row_ = wid * 4 + (W);                                               \
    _Pragma("unroll") for (int c = 0; c < 8; ++c) {                         \
      int d_ = lane * 4 + c * 256;                                          \
      unsigned int lo_ = pack_bf16(xv[W][c].x * (RW), xv[W][c].y * (RW));   \
      unsigned int hi_ = pack_bf16(xv[W][c].z * (RW), xv[W][c].w * (RW));   \
      int raw_ = ((d_ >> 5) << 10) | (((d_ >> 3) & 3) << 8) |               \
                 (row_ << 4) | ((d_ & 7) << 1);                             \
      int pad_ = raw_ + ((raw_ >> 8) << 4);                                 \
      *(uint2*)(abuf + pad_) = make_uint2(lo_, hi_);                        \
    }                                                                       \
  }

extern "C" __global__ __launch_bounds__(256, 2) void k_main(
    const float* __restrict__ x, const float* __restrict__ V,
    const unsigned short* __restrict__ w1f, const float* __restrict__ W2,
    const float* __restrict__ hs_t, float* __restrict__ out) {
  __shared__ __align__(16) unsigned char abuf[69632];  // bf16 A-frags, +16B/256B pad
  __shared__ float cpart[8][256];                      // per-wave partial C tiles
  __shared__ float tbuf[16][24];                       // gelu(T)[row][j]

  int tid = threadIdx.x, lane = tid & 63, wid = tid >> 6;
  int row0 = blockIdx.x * 16 + wid * 4;
  int b = row0 >> 12;
  int s0 = row0 & (S_ - 1);
  int d0 = lane * 4;

  // x stream first (longest latency), then scan values
  float4 xv[4][8];
  const float* xr = x + (size_t)row0 * D_ + d0;
#pragma unroll
  for (int w = 0; w < 4; ++w)
#pragma unroll
    for (int k = 0; k < 8; ++k)
      xv[w][k] = *(const float4*)(xr + w * D_ + k * 256);

  float hv = 0.f;
  if (lane < 4 * RS_) {
    int w = lane / RS_, r = lane - w * RS_;
    hv = hs_t[((size_t)b * RS_ + r) * S_ + s0 + w];
  }

  float4 q0[4], q1[4], q2[4], q3[4];

  // ---- phase b: x2 = x + hs @ V  (depth-3 half-row pipeline) ----
  const float* Vp = V + d0;
  ld4(q0, Vp);
  ld4(q1, Vp + 1024);
  ld4(q2, Vp + D_);
#pragma unroll
  for (int rp = 0; rp < 3; ++rp) {
    int r0 = 2 * rp, r1 = 2 * rp + 1;
    ld4(q3, Vp + r1 * D_ + 1024);
    float h0 = rdlane(hv, 0 * RS_ + r0), h1 = rdlane(hv, 1 * RS_ + r0);
    float h2 = rdlane(hv, 2 * RS_ + r0), h3 = rdlane(hv, 3 * RS_ + r0);
    FMA_HALF(q0, 0, h0, h1, h2, h3);
    if (rp < 2) ld4(q0, Vp + (r0 + 2) * D_);
    FMA_HALF(q1, 4, h0, h1, h2, h3);
    if (rp < 2) ld4(q1, Vp + (r1 + 1) * D_ + 1024);
    float e0 = rdlane(hv, 0 * RS_ + r1), e1 = rdlane(hv, 1 * RS_ + r1);
    float e2 = rdlane(hv, 2 * RS_ + r1), e3 = rdlane(hv, 3 * RS_ + r1);
    FMA_HALF(q2, 0, e0, e1, e2, e3);
    if (rp < 2) ld4(q2, Vp + (r1 + 2) * D_);
    FMA_HALF(q3, 4, e0, e1, e2, e3);
  }

  // rms2 per row
  float s20 = 0.f, s21 = 0.f, s22 = 0.f, s23 = 0.f;
#pragma unroll
  for (int k = 0; k < 8; ++k) {
    s20 += dot4(xv[0][k], xv[0][k]);
    s21 += dot4(xv[1][k], xv[1][k]);
    s22 += dot4(xv[2][k], xv[2][k]);
    s23 += dot4(xv[3][k], xv[3][k]);
  }
  float rinv0 = rsqrtf(wave_sum(s20) * (1.0f / D_) + EPS_);
  float rinv1 = rsqrtf(wave_sum(s21) * (1.0f / D_) + EPS_);
  float rinv2 = rsqrtf(wave_sum(s22) * (1.0f / D_) + EPS_);
  float rinv3 = rsqrtf(wave_sum(s23) * (1.0f / D_) + EPS_);

  // ---- stage A = x2*rinv (bf16) into LDS fragments ----
  STAGE(0, rinv0);
  STAGE(1, rinv1);
  STAGE(2, rinv2);
  STAGE(3, rinv3);
  __syncthreads();

  // ---- GEMM1 via MFMA: T[16x21] = A[16x2048] @ W1hat[2048x21(pad32)] ----
  {
    floatx4 acc0 = {0.f, 0.f, 0.f, 0.f};
    floatx4 acc1 = {0.f, 0.f, 0.f, 0.f};
#pragma unroll 4
    for (int t = 0; t < 16; ++t) {
      int kt = wid * 16 + t;
      int raw = (kt << 10) | ((lane >> 4) << 8) | ((lane & 15) << 4);
      int pad = raw + ((raw >> 8) << 4);
      bf16x8 a = *(const bf16x8*)(abuf + pad);
      bf16x8 b0 = *(const bf16x8*)(w1f + (size_t)(kt * 2 + 0) * 512 + lane * 8);
      bf16x8 b1 = *(const bf16x8*)(w1f + (size_t)(kt * 2 + 1) * 512 + lane * 8);
      acc0 = __builtin_amdgcn_mfma_f32_16x16x32_bf16(a, b0, acc0, 0, 0, 0);
      acc1 = __builtin_amdgcn_mfma_f32_16x16x32_bf16(a, b1, acc1, 0, 0, 0);
    }
    *(floatx4*)&cpart[wid * 2 + 0][lane * 4] = acc0;
    *(floatx4*)&cpart[wid * 2 + 1][lane * 4] = acc1;
  }
  __syncthreads();

  // ---- reduce 4 partials, gelu, scatter to tbuf[row][j] ----
  if (tid < 128) {
    int nt = tid >> 6, pos = tid & 63;
    floatx4 s = *(const floatx4*)&cpart[nt][pos * 4];
    s += *(const floatx4*)&cpart[2 + nt][pos * 4];
    s += *(const floatx4*)&cpart[4 + nt][pos * 4];
    s += *(const floatx4*)&cpart[6 + nt][pos * 4];
    int col = pos & 15, rg = pos >> 4;
    int j = nt * 16 + col;
    if (j < RF_) {
      tbuf[rg * 4 + 0][j] = gelu_f(s.x);
      tbuf[rg * 4 + 1][j] = gelu_f(s.y);
      tbuf[rg * 4 + 2][j] = gelu_f(s.z);
      tbuf[rg * 4 + 3][j] = gelu_f(s.w);
    }
  }
  __syncthreads();

  // owner waves pick up g, lane j holds g[row][j]
  float g0 = (lane < RF_) ? tbuf[wid * 4 + 0][lane] : 0.f;
  float g1 = (lane < RF_) ? tbuf[wid * 4 + 1][lane] : 0.f;
  float g2 = (lane < RF_) ? tbuf[wid * 4 + 2][lane] : 0.f;
  float g3 = (lane < RF_) ? tbuf[wid * 4 + 3][lane] : 0.f;

  // ---- phase d: out = x2 + g @ W2  (depth-3 half-row pipeline, fp32) ----
  const float* W2p = W2 + d0;
  ld4(q0, W2p);
  ld4(q1, W2p + 1024);
  ld4(q2, W2p + D_);
  for (int jp = 0; jp < 10; ++jp) {
    int j0 = 2 * jp, j1 = 2 * jp + 1;
    ld4(q3, W2p + j1 * D_ + 1024);
    float f0 = rdlane(g0, j0), f1 = rdlane(g1, j0);
    float f2 = rdlane(g2, j0), f3 = rdlane(g3, j0);
    FMA_HALF(q0, 0, f0, f1, f2, f3);
    ld4(q0, W2p + (j0 + 2) * D_);
    FMA_HALF(q1, 4, f0, f1, f2, f3);
    ld4(q1, W2p + (j1 + 1) * D_ + 1024);
    float e0 = rdlane(g0, j1), e1 = rdlane(g1, j1);
    float e2 = rdlane(g2, j1), e3 = rdlane(g3, j1);
    FMA_HALF(q2, 0, e0, e1, e2, e3);
    if (jp < 9) ld4(q2, W2p + (j1 + 2) * D_);
    FMA_HALF(q3, 4, e0, e1, e2, e3);
  }
  {
    float f0 = rdlane(g0, 20), f1 = rdlane(g1, 20);
    float f2 = rdlane(g2, 20), f3 = rdlane(g3, 20);
    FMA_HALF(q0, 0, f0, f1, f2, f3);
    FMA_HALF(q1, 4, f0, f1, f2, f3);
  }

  float* orow = out + (size_t)row0 * D_ + d0;
#pragma unroll
  for (int w = 0; w < 4; ++w)
#pragma unroll
    for (int k = 0; k < 8; ++k)
      nt_store4(xv[w][k], orow + w * D_ + k * 256);
}

extern "C" void kernel_launch(void* const* d_in, const int* in_sizes, int n_in,
                              void* d_out, int out_size, void* d_ws, size_t ws_size,
                              hipStream_t stream) {
  const float* x   = (const float*)d_in[0];
  const float* n1w = (const float*)d_in[1];
  const float* U   = (const float*)d_in[2];
  const float* lam = (const float*)d_in[3];
  const float* V   = (const float*)d_in[4];
  const float* n2w = (const float*)d_in[5];
  const float* W1  = (const float*)d_in[6];
  const float* W2  = (const float*)d_in[7];
  float* out = (float*)d_out;
  float* ws  = (float*)d_ws;

  // ws layout (floats): u_t[98304] | hs_t[98304] | w1f[32768 fl = 65536 u16] | ut[12288]
  float* u_t = ws;
  float* hs_t = ws + 98304;
  unsigned short* w1f = (unsigned short*)(ws + 196608);
  float* ut = ws + 229376;

  k_prep<<<304, 256, 0, stream>>>(W1, U, n1w, n2w, w1f, ut);
  k_rms1<<<2048, 256, 0, stream>>>(x, ut, u_t);
  k_scan<<<24, 64, 0, stream>>>(lam, u_t, hs_t);
  k_main<<<1024, 256, 0, stream>>>(x, V, w1f, W2, hs_t, out);
}